// Round 7
// baseline (693.154 us; speedup 1.0000x reference)
//
#include <hip/hip_runtime.h>

typedef __attribute__((ext_vector_type(8))) short s8v;
typedef __attribute__((ext_vector_type(4))) float f4v;

constexpr int BN = 16;
constexpr int TQ = 2048;
constexpr int TK = 2048;
constexpr int DH = 128;

__device__ __forceinline__ unsigned short f2bf(float f) {
  unsigned int u = __float_as_uint(f);
  u += 0x7fffu + ((u >> 16) & 1u);   // round-to-nearest-even
  return (unsigned short)(u >> 16);
}
__device__ __forceinline__ float bf2f(unsigned short h) {
  return __uint_as_float(((unsigned int)h) << 16);
}

// ---------------------------------------------------------------------------
// Kernel 0 (path A): split Q and K f32 -> hi/lo bf16 chunk-planes.
// Layout: [b][chunk(4)][hi|lo][row(2048)][32]  (chunk = d/32, col = d%32)
// so qk staging reads are fully contiguous 1KB-per-wave copies.
// ---------------------------------------------------------------------------
__global__ __launch_bounds__(256) void qksplit_kernel(
    const float* __restrict__ Q, const float* __restrict__ K,
    unsigned short* __restrict__ Qsp, unsigned short* __restrict__ Ksp)
{
  const float* src = blockIdx.y ? K : Q;
  unsigned short* dst = blockIdx.y ? Ksp : Qsp;
  const int tid = threadIdx.x;
  const int rowg = blockIdx.x * 8 + (tid >> 5);   // global row 0..32767
  const int c4 = tid & 31;                        // float4 index within row
  const int b = rowg >> 11, brow = rowg & 2047;
  const int chunk = c4 >> 3, col = (c4 & 7) * 4;  // d = c4*4 -> chunk, col

  float4 v = *(const float4*)(src + (size_t)rowg * DH + c4 * 4);
  unsigned short h0 = f2bf(v.x), h1 = f2bf(v.y), h2 = f2bf(v.z), h3 = f2bf(v.w);
  ushort4 hv = make_ushort4(h0, h1, h2, h3);
  ushort4 lv = make_ushort4(f2bf(v.x - bf2f(h0)), f2bf(v.y - bf2f(h1)),
                            f2bf(v.z - bf2f(h2)), f2bf(v.w - bf2f(h3)));
  size_t pbase = (((size_t)b * 4 + chunk) * 2) * (size_t)TQ * 32 + (size_t)brow * 32 + col;
  *(ushort4*)(dst + pbase) = hv;                        // hi plane
  *(ushort4*)(dst + pbase + (size_t)TQ * 32) = lv;      // lo plane
}

// ---------------------------------------------------------------------------
// Kernel 1 (path A): S = Q K^T / sqrt(D); P = (masked ? 0 : exp(S)) -> Pb bf16;
//                    Z[b,k] += column sums.
// Staging is a pure copy from pre-split planes (no conversion VALU).
// Epilogue: mask restaged to LDS, exp written in-place over it, then
// coalesced uint4 stores (256B row runs) instead of scattered u16 stores.
// ---------------------------------------------------------------------------
union QKSH2 {
  struct {
    unsigned short qhi[128][40];
    unsigned short qlo[128][40];
    unsigned short khi[128][40];
    unsigned short klo[128][40];
  } s;                                  // 40960 B (MFMA phase)
  unsigned short msk[128][136];         // 34816 B (epilogue; 272B rows, 16B-aligned)
};

__global__ __launch_bounds__(256, 4) void qk_exp_split_kernel(
    const unsigned short* __restrict__ Qsp, const unsigned short* __restrict__ Ksp,
    const float* __restrict__ Msk, unsigned short* __restrict__ Pb,
    float* __restrict__ Z)
{
  __shared__ QKSH2 sh;

  const int kb = blockIdx.x, qb = blockIdx.y, b = blockIdx.z;
  const int tid = threadIdx.x;
  const int wave = tid >> 6, lane = tid & 63;
  const int wr = wave >> 1, wc = wave & 1;
  const int quad = lane >> 4, l16 = lane & 15;

  f4v acc[4][4];
#pragma unroll
  for (int i = 0; i < 4; ++i)
#pragma unroll
    for (int j = 0; j < 4; ++j)
      acc[i][j] = (f4v){0.f, 0.f, 0.f, 0.f};

  const unsigned short* QspB = Qsp + (size_t)b * 4 * 2 * TQ * 32;
  const unsigned short* KspB = Ksp + (size_t)b * 4 * 2 * TK * 32;

  for (int chunk = 0; chunk < 4; ++chunk) {
    const unsigned short* qh = QspB + (((size_t)chunk * 2 + 0) * TQ + (size_t)qb * 128) * 32;
    const unsigned short* ql = QspB + (((size_t)chunk * 2 + 1) * TQ + (size_t)qb * 128) * 32;
    const unsigned short* kh = KspB + (((size_t)chunk * 2 + 0) * TK + (size_t)kb * 128) * 32;
    const unsigned short* kl = KspB + (((size_t)chunk * 2 + 1) * TK + (size_t)kb * 128) * 32;
    __syncthreads();
#pragma unroll
    for (int i = 0; i < 2; ++i) {
      int idx = i * 256 + tid;
      int r = idx >> 2, c8 = (idx & 3) * 8;
      *(uint4*)&sh.s.qhi[r][c8] = *(const uint4*)(qh + (size_t)r * 32 + c8);
      *(uint4*)&sh.s.qlo[r][c8] = *(const uint4*)(ql + (size_t)r * 32 + c8);
      *(uint4*)&sh.s.khi[r][c8] = *(const uint4*)(kh + (size_t)r * 32 + c8);
      *(uint4*)&sh.s.klo[r][c8] = *(const uint4*)(kl + (size_t)r * 32 + c8);
    }
    __syncthreads();

    s8v ah[4], al[4];
#pragma unroll
    for (int i = 0; i < 4; ++i) {
      ah[i] = *(const s8v*)&sh.s.qhi[wr*64 + i*16 + l16][quad*8];
      al[i] = *(const s8v*)&sh.s.qlo[wr*64 + i*16 + l16][quad*8];
    }
#pragma unroll
    for (int j = 0; j < 4; ++j) {
      s8v bh = *(const s8v*)&sh.s.khi[wc*64 + j*16 + l16][quad*8];
      s8v bl = *(const s8v*)&sh.s.klo[wc*64 + j*16 + l16][quad*8];
#pragma unroll
      for (int i = 0; i < 4; ++i) {
        acc[i][j] = __builtin_amdgcn_mfma_f32_16x16x32_bf16(ah[i], bh, acc[i][j], 0, 0, 0);
        acc[i][j] = __builtin_amdgcn_mfma_f32_16x16x32_bf16(al[i], bh, acc[i][j], 0, 0, 0);
        acc[i][j] = __builtin_amdgcn_mfma_f32_16x16x32_bf16(ah[i], bl, acc[i][j], 0, 0, 0);
      }
    }
  }

  // ---- mask restage into dead Q/K LDS (ushort 0/1)
  __syncthreads();
  {
    const float* MB = Msk + ((size_t)b * TQ + (size_t)qb * 128) * TK + (size_t)kb * 128;
#pragma unroll
    for (int it = 0; it < 16; ++it) {
      int idx = it * 256 + tid;
      int r = idx >> 5, c = (idx & 31) * 4;
      float4 mv = *(const float4*)(MB + (size_t)r * TK + c);
      ushort4 mu;
      mu.x = (mv.x != 0.f); mu.y = (mv.y != 0.f);
      mu.z = (mv.z != 0.f); mu.w = (mv.w != 0.f);
      *(ushort4*)&sh.msk[r][c] = mu;
    }
  }
  __syncthreads();

  // ---- exp + mask, written IN-PLACE over the mask tile (same thread per cell)
  const float scale = 0.08838834764831845f;  // 1/sqrt(128)
  float csum[4] = {0.f, 0.f, 0.f, 0.f};
#pragma unroll
  for (int i = 0; i < 4; ++i) {
    int lr0 = wr * 64 + i * 16 + quad * 4;
#pragma unroll
    for (int r = 0; r < 4; ++r) {
      unsigned short* mrow = &sh.msk[lr0 + r][wc * 64];
#pragma unroll
      for (int j = 0; j < 4; ++j) {
        unsigned short m = mrow[j * 16 + l16];
        float p = m ? 0.f : __expf(acc[i][j][r] * scale);
        mrow[j * 16 + l16] = f2bf(p);
        csum[j] += p;
      }
    }
  }
  __syncthreads();

  // ---- coalesced bf16 store of the 128x128 P tile
  {
    unsigned short* PbB = Pb + ((size_t)b * TQ + (size_t)qb * 128) * TK + (size_t)kb * 128;
#pragma unroll
    for (int it = 0; it < 8; ++it) {
      int idx = it * 256 + tid;
      int row = idx >> 4, c8 = (idx & 15) * 8;
      *(uint4*)(PbB + (size_t)row * TK + c8) = *(const uint4*)&sh.msk[row][c8];
    }
  }

#pragma unroll
  for (int j = 0; j < 4; ++j) {
    float v = csum[j];
    v += __shfl_xor(v, 16, 64);
    v += __shfl_xor(v, 32, 64);
    if (quad == 0)
      atomicAdd(&Z[b * TK + kb * 128 + wc * 64 + j * 16 + l16], v);
  }
}

// ---------------------------------------------------------------------------
// Round-5 qk kernel (tier B fallback): f32 Q/K input, split in-kernel,
// bf16 P into Pb.
// ---------------------------------------------------------------------------
union QKSH {
  struct {
    unsigned short qhi[128][40];
    unsigned short qlo[128][40];
    unsigned short khi[128][40];
    unsigned short klo[128][40];
  } s;
  unsigned short msk[128][132];
};

__global__ __launch_bounds__(256, 4) void qk_exp_kernel(
    const float* __restrict__ Q, const float* __restrict__ K,
    const float* __restrict__ Msk, unsigned short* __restrict__ Pb,
    float* __restrict__ Z)
{
  __shared__ QKSH sh;

  const int kb = blockIdx.x, qb = blockIdx.y, b = blockIdx.z;
  const int tid = threadIdx.x;
  const int wave = tid >> 6, lane = tid & 63;
  const int wr = wave >> 1, wc = wave & 1;
  const int quad = lane >> 4, l16 = lane & 15;

  f4v acc[4][4];
#pragma unroll
  for (int i = 0; i < 4; ++i)
#pragma unroll
    for (int j = 0; j < 4; ++j)
      acc[i][j] = (f4v){0.f, 0.f, 0.f, 0.f};

  const float* Qb = Q + ((size_t)b * TQ + (size_t)qb * 128) * DH;
  const float* Kb = K + ((size_t)b * TK + (size_t)kb * 128) * DH;

  for (int dc = 0; dc < DH; dc += 32) {
    __syncthreads();
#pragma unroll
    for (int i = 0; i < 4; ++i) {
      int idx = i * 256 + tid;
      int r = idx >> 3, c = (idx & 7) * 4;
      float4 qv = *(const float4*)(Qb + (size_t)r * DH + dc + c);
      float4 kv = *(const float4*)(Kb + (size_t)r * DH + dc + c);
      unsigned short h;
      h = f2bf(qv.x); sh.s.qhi[r][c+0] = h; sh.s.qlo[r][c+0] = f2bf(qv.x - bf2f(h));
      h = f2bf(qv.y); sh.s.qhi[r][c+1] = h; sh.s.qlo[r][c+1] = f2bf(qv.y - bf2f(h));
      h = f2bf(qv.z); sh.s.qhi[r][c+2] = h; sh.s.qlo[r][c+2] = f2bf(qv.z - bf2f(h));
      h = f2bf(qv.w); sh.s.qhi[r][c+3] = h; sh.s.qlo[r][c+3] = f2bf(qv.w - bf2f(h));
      h = f2bf(kv.x); sh.s.khi[r][c+0] = h; sh.s.klo[r][c+0] = f2bf(kv.x - bf2f(h));
      h = f2bf(kv.y); sh.s.khi[r][c+1] = h; sh.s.klo[r][c+1] = f2bf(kv.y - bf2f(h));
      h = f2bf(kv.z); sh.s.khi[r][c+2] = h; sh.s.klo[r][c+2] = f2bf(kv.z - bf2f(h));
      h = f2bf(kv.w); sh.s.khi[r][c+3] = h; sh.s.klo[r][c+3] = f2bf(kv.w - bf2f(h));
    }
    __syncthreads();

    s8v ah[4], al[4];
#pragma unroll
    for (int i = 0; i < 4; ++i) {
      ah[i] = *(const s8v*)&sh.s.qhi[wr*64 + i*16 + l16][quad*8];
      al[i] = *(const s8v*)&sh.s.qlo[wr*64 + i*16 + l16][quad*8];
    }
#pragma unroll
    for (int j = 0; j < 4; ++j) {
      s8v bh = *(const s8v*)&sh.s.khi[wc*64 + j*16 + l16][quad*8];
      s8v bl = *(const s8v*)&sh.s.klo[wc*64 + j*16 + l16][quad*8];
#pragma unroll
      for (int i = 0; i < 4; ++i) {
        acc[i][j] = __builtin_amdgcn_mfma_f32_16x16x32_bf16(ah[i], bh, acc[i][j], 0, 0, 0);
        acc[i][j] = __builtin_amdgcn_mfma_f32_16x16x32_bf16(al[i], bh, acc[i][j], 0, 0, 0);
        acc[i][j] = __builtin_amdgcn_mfma_f32_16x16x32_bf16(ah[i], bl, acc[i][j], 0, 0, 0);
      }
    }
  }

  __syncthreads();
  {
    const float* MB = Msk + ((size_t)b * TQ + (size_t)qb * 128) * TK + (size_t)kb * 128;
#pragma unroll
    for (int it = 0; it < 16; ++it) {
      int idx = it * 256 + tid;
      int r = idx >> 5, c = (idx & 31) * 4;
      float4 mv = *(const float4*)(MB + (size_t)r * TK + c);
      ushort4 mu;
      mu.x = (mv.x != 0.f); mu.y = (mv.y != 0.f);
      mu.z = (mv.z != 0.f); mu.w = (mv.w != 0.f);
      *(ushort4*)&sh.msk[r][c] = mu;
    }
  }
  __syncthreads();

  const float scale = 0.08838834764831845f;
  float csum[4] = {0.f, 0.f, 0.f, 0.f};
#pragma unroll
  for (int i = 0; i < 4; ++i) {
    int lr0 = wr * 64 + i * 16 + quad * 4;
#pragma unroll
    for (int r = 0; r < 4; ++r) {
      size_t rowoff = ((size_t)b * TQ + qb * 128 + lr0 + r) * TK + kb * 128 + wc * 64;
      const unsigned short* mrow = &sh.msk[lr0 + r][wc * 64];
#pragma unroll
      for (int j = 0; j < 4; ++j) {
        unsigned short m = mrow[j * 16 + l16];
        float p = m ? 0.f : __expf(acc[i][j][r] * scale);
        Pb[rowoff + j * 16 + l16] = f2bf(p);
        csum[j] += p;
      }
    }
  }
#pragma unroll
  for (int j = 0; j < 4; ++j) {
    float v = csum[j];
    v += __shfl_xor(v, 16, 64);
    v += __shfl_xor(v, 32, 64);
    if (quad == 0)
      atomicAdd(&Z[b * TK + kb * 128 + wc * 64 + j * 16 + l16], v);
  }
}

// ---------------------------------------------------------------------------
// Kernel 2a: V[b,k,d] -> Vt_hi/Vt_lo[b,d,k] (bf16 split planes) via LDS tile,
// with rz[k] folded in (runs after rz_kernel).
// ---------------------------------------------------------------------------
__global__ __launch_bounds__(256) void vtrans_kernel(
    const float* __restrict__ V, const float* __restrict__ Rz,
    unsigned short* __restrict__ Vthi, unsigned short* __restrict__ Vtlo)
{
  __shared__ float tile[64][65];
  const int k0 = blockIdx.x * 64, d0 = blockIdx.y * 64, b = blockIdx.z;
  const int tid = threadIdx.x;
#pragma unroll
  for (int i = 0; i < 4; ++i) {
    int idx = i * 256 + tid;
    int r = idx >> 4, c = (idx & 15) * 4;
    float4 v = *(const float4*)(V + ((size_t)b * TK + k0 + r) * DH + d0 + c);
    tile[r][c] = v.x; tile[r][c+1] = v.y; tile[r][c+2] = v.z; tile[r][c+3] = v.w;
  }
  __syncthreads();
  const int dr = tid >> 2, kq = (tid & 3) * 16;
  float rzbuf[16];
#pragma unroll
  for (int m = 0; m < 4; ++m) {
    float4 rv = *(const float4*)(Rz + (size_t)b * TK + k0 + kq + 4 * m);
    rzbuf[4*m] = rv.x; rzbuf[4*m+1] = rv.y; rzbuf[4*m+2] = rv.z; rzbuf[4*m+3] = rv.w;
  }
  size_t base = ((size_t)b * DH + d0 + dr) * TK + k0 + kq;
  unsigned short hbuf[16], lbuf[16];
#pragma unroll
  for (int j = 0; j < 16; ++j) {
    float f = tile[kq + j][dr] * rzbuf[j];
    unsigned short h = f2bf(f);
    hbuf[j] = h;
    lbuf[j] = f2bf(f - bf2f(h));
  }
#pragma unroll
  for (int m = 0; m < 4; ++m) {
    ushort4 hv = make_ushort4(hbuf[4*m], hbuf[4*m+1], hbuf[4*m+2], hbuf[4*m+3]);
    ushort4 lv = make_ushort4(lbuf[4*m], lbuf[4*m+1], lbuf[4*m+2], lbuf[4*m+3]);
    *(ushort4*)(Vthi + base + 4*m) = hv;
    *(ushort4*)(Vtlo + base + 4*m) = lv;
  }
}

// Kernel 2b: Rz = 1/Z
__global__ __launch_bounds__(256) void rz_kernel(const float* __restrict__ Z,
                                                 float* __restrict__ Rz) {
  int i = blockIdx.x * 256 + threadIdx.x;
  Rz[i] = 1.0f / Z[i];
}

// ---------------------------------------------------------------------------
// Kernel 3: attn = bf2f(Pb)*rz (f32 out), context = Pb @ (V*rz).
// ---------------------------------------------------------------------------
union __align__(16) AVSH {
  struct {
    unsigned short a[64][40];
    unsigned short vh[128][40];
    unsigned short vl[128][40];
  } b[2];                        // 50 KB double buffer
  float ctx[64][131];
};

__global__ __launch_bounds__(256) void av_kernel_b(
    const unsigned short* __restrict__ Pb, float* __restrict__ Attn,
    const unsigned short* __restrict__ Vthi, const unsigned short* __restrict__ Vtlo,
    const float* __restrict__ Rz, float* __restrict__ Ctx)
{
  __shared__ AVSH sh;
  const int qb = blockIdx.x, b = blockIdx.y;
  const int tid = threadIdx.x;
  const int wave = tid >> 6, lane = tid & 63;
  const int wr = wave >> 1, wc = wave & 1;
  const int quad = lane >> 4, l16 = lane & 15;

  f4v acc[4][2];
#pragma unroll
  for (int i = 0; i < 4; ++i)
#pragma unroll
    for (int j = 0; j < 2; ++j)
      acc[i][j] = (f4v){0.f, 0.f, 0.f, 0.f};

  const unsigned short* pbB = Pb + ((size_t)b * TQ + (size_t)qb * 64) * TK;
  float* attnB = Attn + ((size_t)b * TQ + (size_t)qb * 64) * TK;
  const unsigned short* vhB = Vthi + (size_t)b * DH * TK;
  const unsigned short* vlB = Vtlo + (size_t)b * DH * TK;
  const float* rzB = Rz + (size_t)b * TK;

  const int ar = tid >> 2, ac = (tid & 3) * 8;
  const int vr = tid >> 2, vc = (tid & 3) * 8;

  s8v pa;
  float4 rz0, rz1;
  uint4 vh0, vh1, vl0, vl1;

  auto load_chunk = [&](int kc) {
    pa  = *(const s8v*)(pbB + (size_t)ar * TK + kc + ac);
    rz0 = *(const float4*)(rzB + kc + ac);
    rz1 = *(const float4*)(rzB + kc + ac + 4);
    vh0 = *(const uint4*)(vhB + (size_t)vr * TK + kc + vc);
    vh1 = *(const uint4*)(vhB + (size_t)(vr + 64) * TK + kc + vc);
    vl0 = *(const uint4*)(vlB + (size_t)vr * TK + kc + vc);
    vl1 = *(const uint4*)(vlB + (size_t)(vr + 64) * TK + kc + vc);
  };

  auto stage_chunk = [&](int kc, int B) {
    float4 w0, w1;
    w0.x = bf2f((unsigned short)pa[0]) * rz0.x;
    w0.y = bf2f((unsigned short)pa[1]) * rz0.y;
    w0.z = bf2f((unsigned short)pa[2]) * rz0.z;
    w0.w = bf2f((unsigned short)pa[3]) * rz0.w;
    w1.x = bf2f((unsigned short)pa[4]) * rz1.x;
    w1.y = bf2f((unsigned short)pa[5]) * rz1.y;
    w1.z = bf2f((unsigned short)pa[6]) * rz1.z;
    w1.w = bf2f((unsigned short)pa[7]) * rz1.w;
    *(float4*)(attnB + (size_t)ar * TK + kc + ac) = w0;
    *(float4*)(attnB + (size_t)ar * TK + kc + ac + 4) = w1;
    *(s8v*)&sh.b[B].a[ar][ac] = pa;
    *(uint4*)&sh.b[B].vh[vr][vc] = vh0;
    *(uint4*)&sh.b[B].vh[vr + 64][vc] = vh1;
    *(uint4*)&sh.b[B].vl[vr][vc] = vl0;
    *(uint4*)&sh.b[B].vl[vr + 64][vc] = vl1;
  };

  load_chunk(0);
  stage_chunk(0, 0);
  __syncthreads();

  int cur = 0;
  constexpr int NT = TK / 32;
  for (int t = 0; t < NT; ++t) {
    if (t + 1 < NT) load_chunk((t + 1) * 32);

    s8v vhf[4], vlf[4], pf[2];
#pragma unroll
    for (int i = 0; i < 4; ++i) {
      vhf[i] = *(const s8v*)&sh.b[cur].vh[wr * 64 + i * 16 + l16][quad * 8];
      vlf[i] = *(const s8v*)&sh.b[cur].vl[wr * 64 + i * 16 + l16][quad * 8];
    }
#pragma unroll
    for (int j = 0; j < 2; ++j)
      pf[j] = *(const s8v*)&sh.b[cur].a[wc * 32 + j * 16 + l16][quad * 8];

#pragma unroll
    for (int i = 0; i < 4; ++i)
#pragma unroll
      for (int j = 0; j < 2; ++j) {
        acc[i][j] = __builtin_amdgcn_mfma_f32_16x16x32_bf16(vhf[i], pf[j], acc[i][j], 0, 0, 0);
        acc[i][j] = __builtin_amdgcn_mfma_f32_16x16x32_bf16(vlf[i], pf[j], acc[i][j], 0, 0, 0);
      }

    if (t + 1 < NT) {
      stage_chunk((t + 1) * 32, cur ^ 1);
      __syncthreads();
      cur ^= 1;
    }
  }

  __syncthreads();
#pragma unroll
  for (int i = 0; i < 4; ++i)
#pragma unroll
    for (int j = 0; j < 2; ++j)
#pragma unroll
      for (int r = 0; r < 4; ++r)
        sh.ctx[wc * 32 + j * 16 + l16][wr * 64 + i * 16 + quad * 4 + r] = acc[i][j][r];
  __syncthreads();
#pragma unroll
  for (int it = 0; it < 8; ++it) {
    int idx = it * 256 + tid;
    int r = idx >> 5, c = (idx & 31) * 4;
    float4 v;
    v.x = sh.ctx[r][c];     v.y = sh.ctx[r][c + 1];
    v.z = sh.ctx[r][c + 2]; v.w = sh.ctx[r][c + 3];
    *(float4*)(Ctx + ((size_t)b * TQ + qb * 64 + r) * DH + c) = v;
  }
}

// ---------------------------------------------------------------------------
extern "C" void kernel_launch(void* const* d_in, const int* in_sizes, int n_in,
                              void* d_out, int out_size, void* d_ws, size_t ws_size,
                              hipStream_t stream)
{
  const float* Q = (const float*)d_in[0];
  const float* K = (const float*)d_in[1];
  const float* V = (const float*)d_in[2];
  const float* M = (const float*)d_in[3];

  float* ctx  = (float*)d_out;
  float* attn = ctx + (size_t)BN * TQ * DH;   // outputs: context ++ attn

  char* ws = (char*)d_ws;
  const size_t pbBytes = (size_t)BN * TQ * TK * 2;   // 128 MiB
  const size_t needA = (67ull << 20) + pbBytes;      // Qsp@1M + Ksp@34M + Pb@67M

  if (ws_size >= needA) {
    // Path A: Z@0 | Rz@512K | Qsp@1M(16M) | Ksp@34M(16M) | Pb@67M(128M)
    //         (Vthi@1M, Vtlo@10M reuse the Qsp region after qk finishes)
    float* Z  = (float*)ws;
    float* Rz = (float*)(ws + (512 << 10));
    unsigned short* Qsp  = (unsigned short*)(ws + (1ull << 20));
    unsigned short* Ksp  = (unsigned short*)(ws + (34ull << 20));
    unsigned short* Pb   = (unsigned short*)(ws + (67ull << 20));
    unsigned short* Vthi = (unsigned short*)(ws + (1ull << 20));
    unsigned short* Vtlo = (unsigned short*)(ws + (10ull << 20));

    hipMemsetAsync(Z, 0, (size_t)BN * TK * sizeof(float), stream);
    qksplit_kernel<<<dim3(BN * TQ / 8, 2), 256, 0, stream>>>(Q, K, Qsp, Ksp);
    qk_exp_split_kernel<<<dim3(TK/128, TQ/128, BN), 256, 0, stream>>>(Qsp, Ksp, M, Pb, Z);
    rz_kernel<<<dim3((BN*TK)/256), 256, 0, stream>>>(Z, Rz);
    vtrans_kernel<<<dim3(TK/64, DH/64, BN), 256, 0, stream>>>(V, Rz, Vthi, Vtlo);
    av_kernel_b<<<dim3(TQ/64, BN), 256, 0, stream>>>(Pb, attn, Vthi, Vtlo, Rz, ctx);
  } else {
    // Path B: round-5 pipeline (proven): Z@0 | Rz@512K | Vthi@1M | Vtlo@10M | Pb@19M
    float* Z  = (float*)ws;
    float* Rz = (float*)(ws + (512 << 10));
    unsigned short* Vthi = (unsigned short*)(ws + (1u << 20));
    unsigned short* Vtlo = (unsigned short*)(ws + (10u << 20));
    unsigned short* Pb   = (unsigned short*)(ws + (19u << 20));

    hipMemsetAsync(Z, 0, (size_t)BN * TK * sizeof(float), stream);
    qk_exp_kernel<<<dim3(TK/128, TQ/128, BN), 256, 0, stream>>>(Q, K, M, Pb, Z);
    rz_kernel<<<dim3((BN*TK)/256), 256, 0, stream>>>(Z, Rz);
    vtrans_kernel<<<dim3(TK/64, DH/64, BN), 256, 0, stream>>>(V, Rz, Vthi, Vtlo);
    av_kernel_b<<<dim3(TQ/64, BN), 256, 0, stream>>>(Pb, attn, Vthi, Vtlo, Rz, ctx);
  }
}

// Round 9
// 656.132 us; speedup vs baseline: 1.0564x; 1.0564x over previous
//
#include <hip/hip_runtime.h>

typedef __attribute__((ext_vector_type(8))) short s8v;
typedef __attribute__((ext_vector_type(4))) float f4v;

constexpr int BN = 16;
constexpr int TQ = 2048;
constexpr int TK = 2048;
constexpr int DH = 128;

__device__ __forceinline__ unsigned short f2bf(float f) {
  unsigned int u = __float_as_uint(f);
  u += 0x7fffu + ((u >> 16) & 1u);   // round-to-nearest-even
  return (unsigned short)(u >> 16);
}
__device__ __forceinline__ float bf2f(unsigned short h) {
  return __uint_as_float(((unsigned int)h) << 16);
}

// ---------------------------------------------------------------------------
// Kernel 1: S = Q K^T / sqrt(D); P = (masked ? 0 : exp(S)) -> Pb bf16;
//           Z[b,k] += column sums (softmax is over the q axis!).
// Round-5 structure (f32 Q/K split in-kernel, scattered Pb store epilogue),
// plus: mask tile prefetched into registers during the MFMA chunks
// (issue-early / convert-late), so the formerly-serial 16-load mask phase
// costs ~0 extra latency. launch_bounds relaxed 4->3 waves/EU for the
// +48 VGPR of in-flight mask state (round 5 sat exactly at the 128 cap).
// ---------------------------------------------------------------------------
union QKSH {
  struct {
    unsigned short qhi[128][40];
    unsigned short qlo[128][40];
    unsigned short khi[128][40];
    unsigned short klo[128][40];
  } s;                                  // 40960 B (MFMA phase)
  unsigned short msk[128][132];         // 33792 B (epilogue phase)
};

__global__ __launch_bounds__(256, 3) void qk_exp_kernel(
    const float* __restrict__ Q, const float* __restrict__ K,
    const float* __restrict__ Msk, unsigned short* __restrict__ Pb,
    float* __restrict__ Z)
{
  __shared__ QKSH sh;

  const int kb = blockIdx.x, qb = blockIdx.y, b = blockIdx.z;
  const int tid = threadIdx.x;
  const int wave = tid >> 6, lane = tid & 63;
  const int wr = wave >> 1, wc = wave & 1;
  const int quad = lane >> 4, l16 = lane & 15;

  f4v acc[4][4];
#pragma unroll
  for (int i = 0; i < 4; ++i)
#pragma unroll
    for (int j = 0; j < 4; ++j)
      acc[i][j] = (f4v){0.f, 0.f, 0.f, 0.f};

  const float* Qb = Q + ((size_t)b * TQ + (size_t)qb * 128) * DH;
  const float* Kb = K + ((size_t)b * TK + (size_t)kb * 128) * DH;
  const float* MB = Msk + ((size_t)b * TQ + (size_t)qb * 128) * TK + (size_t)kb * 128;

  ushort4 mu[16];   // converted mask quarters (0/1), written to LDS after loop

#pragma unroll
  for (int ch = 0; ch < 4; ++ch) {
    const int dc = ch * 32;
    __syncthreads();
#pragma unroll
    for (int i = 0; i < 4; ++i) {
      int idx = i * 256 + tid;
      int r = idx >> 3, c = (idx & 7) * 4;
      float4 qv = *(const float4*)(Qb + (size_t)r * DH + dc + c);
      float4 kv = *(const float4*)(Kb + (size_t)r * DH + dc + c);
      unsigned short h;
      h = f2bf(qv.x); sh.s.qhi[r][c+0] = h; sh.s.qlo[r][c+0] = f2bf(qv.x - bf2f(h));
      h = f2bf(qv.y); sh.s.qhi[r][c+1] = h; sh.s.qlo[r][c+1] = f2bf(qv.y - bf2f(h));
      h = f2bf(qv.z); sh.s.qhi[r][c+2] = h; sh.s.qlo[r][c+2] = f2bf(qv.z - bf2f(h));
      h = f2bf(qv.w); sh.s.qhi[r][c+3] = h; sh.s.qlo[r][c+3] = f2bf(qv.w - bf2f(h));
      h = f2bf(kv.x); sh.s.khi[r][c+0] = h; sh.s.klo[r][c+0] = f2bf(kv.x - bf2f(h));
      h = f2bf(kv.y); sh.s.khi[r][c+1] = h; sh.s.klo[r][c+1] = f2bf(kv.y - bf2f(h));
      h = f2bf(kv.z); sh.s.khi[r][c+2] = h; sh.s.klo[r][c+2] = f2bf(kv.z - bf2f(h));
      h = f2bf(kv.w); sh.s.khi[r][c+3] = h; sh.s.klo[r][c+3] = f2bf(kv.w - bf2f(h));
    }
    __syncthreads();

    // issue this chunk's quarter of the mask tile (drains under the MFMAs)
    float4 mld[4];
#pragma unroll
    for (int t = 0; t < 4; ++t) {
      int idx = (ch * 4 + t) * 256 + tid;
      int r = idx >> 5, c = (idx & 31) * 4;
      mld[t] = *(const float4*)(MB + (size_t)r * TK + c);
    }

    s8v ah[4], al[4];
#pragma unroll
    for (int i = 0; i < 4; ++i) {
      ah[i] = *(const s8v*)&sh.s.qhi[wr*64 + i*16 + l16][quad*8];
      al[i] = *(const s8v*)&sh.s.qlo[wr*64 + i*16 + l16][quad*8];
    }
#pragma unroll
    for (int j = 0; j < 4; ++j) {
      s8v bh = *(const s8v*)&sh.s.khi[wc*64 + j*16 + l16][quad*8];
      s8v bl = *(const s8v*)&sh.s.klo[wc*64 + j*16 + l16][quad*8];
#pragma unroll
      for (int i = 0; i < 4; ++i) {
        acc[i][j] = __builtin_amdgcn_mfma_f32_16x16x32_bf16(ah[i], bh, acc[i][j], 0, 0, 0);
        acc[i][j] = __builtin_amdgcn_mfma_f32_16x16x32_bf16(al[i], bh, acc[i][j], 0, 0, 0);
        acc[i][j] = __builtin_amdgcn_mfma_f32_16x16x32_bf16(ah[i], bl, acc[i][j], 0, 0, 0);
      }
    }

    // convert this chunk's quarter (waitcnt lands after the MFMA cluster)
#pragma unroll
    for (int t = 0; t < 4; ++t) {
      mu[ch * 4 + t] = make_ushort4(mld[t].x != 0.f, mld[t].y != 0.f,
                                    mld[t].z != 0.f, mld[t].w != 0.f);
    }
  }

  // ---- Q/K LDS dead; write prefetched mask bits
  __syncthreads();
#pragma unroll
  for (int t = 0; t < 16; ++t) {
    int idx = t * 256 + tid;
    int r = idx >> 5, c = (idx & 31) * 4;
    *(ushort4*)&sh.msk[r][c] = mu[t];
  }
  __syncthreads();

  const float scale = 0.08838834764831845f;  // 1/sqrt(128)
  float csum[4] = {0.f, 0.f, 0.f, 0.f};
#pragma unroll
  for (int i = 0; i < 4; ++i) {
    int lr0 = wr * 64 + i * 16 + quad * 4;     // local row within tile
#pragma unroll
    for (int r = 0; r < 4; ++r) {
      size_t rowoff = ((size_t)b * TQ + qb * 128 + lr0 + r) * TK + kb * 128 + wc * 64;
      const unsigned short* mrow = &sh.msk[lr0 + r][wc * 64];
#pragma unroll
      for (int j = 0; j < 4; ++j) {
        unsigned short m = mrow[j * 16 + l16];
        float p = m ? 0.f : __expf(acc[i][j][r] * scale);
        Pb[rowoff + j * 16 + l16] = f2bf(p);   // f2bf(0)==0 exactly
        csum[j] += p;
      }
    }
  }
#pragma unroll
  for (int j = 0; j < 4; ++j) {
    float v = csum[j];
    v += __shfl_xor(v, 16, 64);
    v += __shfl_xor(v, 32, 64);
    if (quad == 0)
      atomicAdd(&Z[b * TK + kb * 128 + wc * 64 + j * 16 + l16], v);
  }
}

// ---------------------------------------------------------------------------
// Kernel 2a: V[b,k,d] -> Vt_hi/Vt_lo[b,d,k] (bf16 split planes) via LDS tile,
// with rz[k] folded in (runs after rz_kernel). (round-5 verbatim)
// ---------------------------------------------------------------------------
__global__ __launch_bounds__(256) void vtrans_kernel(
    const float* __restrict__ V, const float* __restrict__ Rz,
    unsigned short* __restrict__ Vthi, unsigned short* __restrict__ Vtlo)
{
  __shared__ float tile[64][65];
  const int k0 = blockIdx.x * 64, d0 = blockIdx.y * 64, b = blockIdx.z;
  const int tid = threadIdx.x;
#pragma unroll
  for (int i = 0; i < 4; ++i) {
    int idx = i * 256 + tid;
    int r = idx >> 4, c = (idx & 15) * 4;
    float4 v = *(const float4*)(V + ((size_t)b * TK + k0 + r) * DH + d0 + c);
    tile[r][c] = v.x; tile[r][c+1] = v.y; tile[r][c+2] = v.z; tile[r][c+3] = v.w;
  }
  __syncthreads();
  const int dr = tid >> 2, kq = (tid & 3) * 16;
  float rzbuf[16];
#pragma unroll
  for (int m = 0; m < 4; ++m) {
    float4 rv = *(const float4*)(Rz + (size_t)b * TK + k0 + kq + 4 * m);
    rzbuf[4*m] = rv.x; rzbuf[4*m+1] = rv.y; rzbuf[4*m+2] = rv.z; rzbuf[4*m+3] = rv.w;
  }
  size_t base = ((size_t)b * DH + d0 + dr) * TK + k0 + kq;
  unsigned short hbuf[16], lbuf[16];
#pragma unroll
  for (int j = 0; j < 16; ++j) {
    float f = tile[kq + j][dr] * rzbuf[j];
    unsigned short h = f2bf(f);
    hbuf[j] = h;
    lbuf[j] = f2bf(f - bf2f(h));
  }
#pragma unroll
  for (int m = 0; m < 4; ++m) {
    ushort4 hv = make_ushort4(hbuf[4*m], hbuf[4*m+1], hbuf[4*m+2], hbuf[4*m+3]);
    ushort4 lv = make_ushort4(lbuf[4*m], lbuf[4*m+1], lbuf[4*m+2], lbuf[4*m+3]);
    *(ushort4*)(Vthi + base + 4*m) = hv;
    *(ushort4*)(Vtlo + base + 4*m) = lv;
  }
}

// Kernel 2b: Rz = 1/Z
__global__ __launch_bounds__(256) void rz_kernel(const float* __restrict__ Z,
                                                 float* __restrict__ Rz) {
  int i = blockIdx.x * 256 + threadIdx.x;
  Rz[i] = 1.0f / Z[i];
}

// ---------------------------------------------------------------------------
// Kernel 3: attn = bf2f(Pb)*rz (f32 out), context = Pb @ (V*rz).
// (round-5 verbatim)
// ---------------------------------------------------------------------------
union __align__(16) AVSH {
  struct {
    unsigned short a[64][40];
    unsigned short vh[128][40];
    unsigned short vl[128][40];
  } b[2];                        // 50 KB double buffer
  float ctx[64][131];
};

__global__ __launch_bounds__(256) void av_kernel_b(
    const unsigned short* __restrict__ Pb, float* __restrict__ Attn,
    const unsigned short* __restrict__ Vthi, const unsigned short* __restrict__ Vtlo,
    const float* __restrict__ Rz, float* __restrict__ Ctx)
{
  __shared__ AVSH sh;
  const int qb = blockIdx.x, b = blockIdx.y;
  const int tid = threadIdx.x;
  const int wave = tid >> 6, lane = tid & 63;
  const int wr = wave >> 1, wc = wave & 1;
  const int quad = lane >> 4, l16 = lane & 15;

  f4v acc[4][2];
#pragma unroll
  for (int i = 0; i < 4; ++i)
#pragma unroll
    for (int j = 0; j < 2; ++j)
      acc[i][j] = (f4v){0.f, 0.f, 0.f, 0.f};

  const unsigned short* pbB = Pb + ((size_t)b * TQ + (size_t)qb * 64) * TK;
  float* attnB = Attn + ((size_t)b * TQ + (size_t)qb * 64) * TK;
  const unsigned short* vhB = Vthi + (size_t)b * DH * TK;
  const unsigned short* vlB = Vtlo + (size_t)b * DH * TK;
  const float* rzB = Rz + (size_t)b * TK;

  const int ar = tid >> 2, ac = (tid & 3) * 8;
  const int vr = tid >> 2, vc = (tid & 3) * 8;

  s8v pa;
  float4 rz0, rz1;
  uint4 vh0, vh1, vl0, vl1;

  auto load_chunk = [&](int kc) {
    pa  = *(const s8v*)(pbB + (size_t)ar * TK + kc + ac);
    rz0 = *(const float4*)(rzB + kc + ac);
    rz1 = *(const float4*)(rzB + kc + ac + 4);
    vh0 = *(const uint4*)(vhB + (size_t)vr * TK + kc + vc);
    vh1 = *(const uint4*)(vhB + (size_t)(vr + 64) * TK + kc + vc);
    vl0 = *(const uint4*)(vlB + (size_t)vr * TK + kc + vc);
    vl1 = *(const uint4*)(vlB + (size_t)(vr + 64) * TK + kc + vc);
  };

  auto stage_chunk = [&](int kc, int B) {
    float4 w0, w1;
    w0.x = bf2f((unsigned short)pa[0]) * rz0.x;
    w0.y = bf2f((unsigned short)pa[1]) * rz0.y;
    w0.z = bf2f((unsigned short)pa[2]) * rz0.z;
    w0.w = bf2f((unsigned short)pa[3]) * rz0.w;
    w1.x = bf2f((unsigned short)pa[4]) * rz1.x;
    w1.y = bf2f((unsigned short)pa[5]) * rz1.y;
    w1.z = bf2f((unsigned short)pa[6]) * rz1.z;
    w1.w = bf2f((unsigned short)pa[7]) * rz1.w;
    *(float4*)(attnB + (size_t)ar * TK + kc + ac) = w0;
    *(float4*)(attnB + (size_t)ar * TK + kc + ac + 4) = w1;
    *(s8v*)&sh.b[B].a[ar][ac] = pa;
    *(uint4*)&sh.b[B].vh[vr][vc] = vh0;
    *(uint4*)&sh.b[B].vh[vr + 64][vc] = vh1;
    *(uint4*)&sh.b[B].vl[vr][vc] = vl0;
    *(uint4*)&sh.b[B].vl[vr + 64][vc] = vl1;
  };

  load_chunk(0);
  stage_chunk(0, 0);
  __syncthreads();

  int cur = 0;
  constexpr int NT = TK / 32;
  for (int t = 0; t < NT; ++t) {
    if (t + 1 < NT) load_chunk((t + 1) * 32);

    s8v vhf[4], vlf[4], pf[2];
#pragma unroll
    for (int i = 0; i < 4; ++i) {
      vhf[i] = *(const s8v*)&sh.b[cur].vh[wr * 64 + i * 16 + l16][quad * 8];
      vlf[i] = *(const s8v*)&sh.b[cur].vl[wr * 64 + i * 16 + l16][quad * 8];
    }
#pragma unroll
    for (int j = 0; j < 2; ++j)
      pf[j] = *(const s8v*)&sh.b[cur].a[wc * 32 + j * 16 + l16][quad * 8];

#pragma unroll
    for (int i = 0; i < 4; ++i)
#pragma unroll
      for (int j = 0; j < 2; ++j) {
        acc[i][j] = __builtin_amdgcn_mfma_f32_16x16x32_bf16(vhf[i], pf[j], acc[i][j], 0, 0, 0);
        acc[i][j] = __builtin_amdgcn_mfma_f32_16x16x32_bf16(vlf[i], pf[j], acc[i][j], 0, 0, 0);
      }

    if (t + 1 < NT) {
      stage_chunk((t + 1) * 32, cur ^ 1);
      __syncthreads();
      cur ^= 1;
    }
  }

  __syncthreads();
#pragma unroll
  for (int i = 0; i < 4; ++i)
#pragma unroll
    for (int j = 0; j < 2; ++j)
#pragma unroll
      for (int r = 0; r < 4; ++r)
        sh.ctx[wc * 32 + j * 16 + l16][wr * 64 + i * 16 + quad * 4 + r] = acc[i][j][r];
  __syncthreads();
#pragma unroll
  for (int it = 0; it < 8; ++it) {
    int idx = it * 256 + tid;
    int r = idx >> 5, c = (idx & 31) * 4;
    float4 v;
    v.x = sh.ctx[r][c];     v.y = sh.ctx[r][c + 1];
    v.z = sh.ctx[r][c + 2]; v.w = sh.ctx[r][c + 3];
    *(float4*)(Ctx + ((size_t)b * TQ + qb * 64 + r) * DH + c) = v;
  }
}

// ---------------------------------------------------------------------------
extern "C" void kernel_launch(void* const* d_in, const int* in_sizes, int n_in,
                              void* d_out, int out_size, void* d_ws, size_t ws_size,
                              hipStream_t stream)
{
  const float* Q = (const float*)d_in[0];
  const float* K = (const float*)d_in[1];
  const float* V = (const float*)d_in[2];
  const float* M = (const float*)d_in[3];

  float* ctx  = (float*)d_out;
  float* attn = ctx + (size_t)BN * TQ * DH;   // outputs: context ++ attn

  // workspace layout (proven >=195MB available in round 7):
  //   Z@0 (128K) | Rz@512K (128K) | Vthi@1M (8M) | Vtlo@10M (8M) | Pb@19M (128M)
  char* ws = (char*)d_ws;
  float* Z  = (float*)ws;
  float* Rz = (float*)(ws + (512 << 10));
  unsigned short* Vthi = (unsigned short*)(ws + (1u << 20));
  unsigned short* Vtlo = (unsigned short*)(ws + (10u << 20));
  unsigned short* Pb   = (unsigned short*)(ws + (19u << 20));

  hipMemsetAsync(Z, 0, (size_t)BN * TK * sizeof(float), stream);
  qk_exp_kernel<<<dim3(TK/128, TQ/128, BN), 256, 0, stream>>>(Q, K, M, Pb, Z);
  rz_kernel<<<dim3((BN*TK)/256), 256, 0, stream>>>(Z, Rz);
  vtrans_kernel<<<dim3(TK/64, DH/64, BN), 256, 0, stream>>>(V, Rz, Vthi, Vtlo);
  av_kernel_b<<<dim3(TQ/64, BN), 256, 0, stream>>>(Pb, attn, Vthi, Vtlo, Rz, ctx);
}